// Round 15
// baseline (49.086 us; speedup 1.0000x reference)
//
#include <hip/hip_runtime.h>
#include <stdint.h>

// AggFeatureModel, FUSED, 2-waves-per-row (T==2048 path), r15:
//  r14 structure; DOW mask-gen accelerated via v_perm SIGN-REPLICATION
//  (CDNA V_PERM_B32 sel 8-11 = 0xFF iff sign of odd byte of {S0,S1}):
//  mask = perm(su<<8, su, 0x090B080A) -- 2 full-rate ops vs and/shr/mul.
//  Semantics are RUNTIME-PROBED (r5 lesson: never gamble on encoding
//  semantics): perm_probe tests HW on opaque inputs, writes flag to d_ws;
//  main kernel branches (wave-uniform) into fast/safe templated bodies.
// Fallback: proven r6 bf16 single-pass kernel for T != 2048 / tiny ws.

#define NCOL 456
static constexpr float EPS = 1e-9f;

typedef __bf16 bf16x8 __attribute__((ext_vector_type(8)));
typedef float  f32x4  __attribute__((ext_vector_type(4)));
typedef int    i32x8  __attribute__((ext_vector_type(8)));
typedef unsigned int u32x4 __attribute__((ext_vector_type(4)));
typedef short  s16x2  __attribute__((ext_vector_type(2)));

__device__ __forceinline__ uint32_t hw_eqmask(uint32_t h) {
    // halfword SWAR eq-zero (legacy kernel)
    const uint32_t s = 0x80008000u - h;
    const s16x2 m = __builtin_bit_cast(s16x2, s) >> 15;
    return __builtin_bit_cast(uint32_t, m);
}

__device__ __forceinline__ uint32_t pack_lobytes(int4 m) {
    // [w0,z0,y0,x0] from the low bytes of 4 ints: 3 v_perm (r10-proven)
    const uint32_t p01 = __builtin_amdgcn_perm((uint32_t)m.y, (uint32_t)m.x, 0x00000400u);
    const uint32_t p23 = __builtin_amdgcn_perm((uint32_t)m.w, (uint32_t)m.z, 0x00000400u);
    return __builtin_amdgcn_perm(p23, p01, 0x05040100u);
}

// byte-sign -> 0xFF/0x00 mask via v_perm sign-replication (sel 8-11 =
// sign of odd bytes of {S0,S1}; su<<8 exposes even-byte signs as odd).
__device__ __forceinline__ uint32_t signmask_perm(uint32_t s) {
    return __builtin_amdgcn_perm(s << 8, s, 0x090B080Au);
}

template<int FAST>
__device__ __forceinline__ void dow_masks(uint32_t kx, uint32_t& mu, uint32_t& mt) {
    if constexpr (FAST) {
        const uint32_t su = 0x80808080u - (kx & 0x0f0f0f0fu);
        mu = signmask_perm(su);
        const uint32_t st = 0x80808080u - ((kx >> 4) & 0x0f0f0f0fu);
        mt = signmask_perm(st);
    } else {
        const uint32_t hu = kx & 0x0f0f0f0fu;
        mu = (((0x80808080u - hu) & 0x80808080u) >> 7) * 255u;
        const uint32_t ht = (kx >> 4) & 0x0f0f0f0fu;
        mt = (((0x80808080u - ht) & 0x80808080u) >> 7) * 255u;
    }
}

// ---------------- HW semantics probe (1 launch, writes flag to d_ws) ----------------
__global__ void perm_probe(uint32_t* flag) {
    if (threadIdx.x == 0) {
        uint32_t ok = 1;
        uint32_t tv[4] = {0x80808080u, 0x00800080u, 0x7F00FF80u, 0x00000000u};
#pragma unroll
        for (int i = 0; i < 4; ++i) {
            uint32_t s = tv[i];
            asm volatile("" : "+v"(s));             // opaque: force HW evaluation
            const uint32_t fast = signmask_perm(s);
            const uint32_t safe = ((s & 0x80808080u) >> 7) * 255u;
            if (fast != safe) ok = 0;
        }
        *flag = ok;
    }
}

// wave LDS slice (uint32 words): [0,256) fp8 val, [256,512) mcc keys,
// [528,784) tr keys (+16-word pad separates broadcast-group banks).
// After consume, slice is reused as the wave's 528-float stat table.
#define WSTR 784
#define MOFF 256
#define TOFF 528

template<int FAST>
__device__ __forceinline__ void agg_body(
    const float4* __restrict__ a4, const int4* __restrict__ m4,
    const int4* __restrict__ t4, const int* __restrict__ seq_lens,
    float* __restrict__ out, uint32_t* smem, float (*scal)[2],
    int row, int lane, int wv)
{
    const int n    = lane & 15;
    const int grp  = lane >> 4;
    const bool istr = (grp >= 2);
    const int ntc  = istr ? ((n - 7) & 15) : n;
    const uint32_t patB = (uint32_t)(((ntc << 4) | n) * 0x01010101u);

    uint32_t* ws = smem + wv * WSTR;

    f32x4 accC = {0.f,0.f,0.f,0.f};
    f32x4 accS = {0.f,0.f,0.f,0.f};
    f32x4 accQ = {0.f,0.f,0.f,0.f};
    float s_p = 0.f, q_p = 0.f;

    const uint8_t* pv = (const uint8_t*)ws + ((grp & 1) << 5);
    const uint8_t* pk = (const uint8_t*)(ws + (istr ? TOFF : MOFF)) + ((grp & 1) << 5);

    // ---- stage this wave's half-row: 4 x {float4,int4,int4}, coalesced ----
    const size_t g4 = (size_t)row * 512 + wv * 256;   // float4 units
#pragma unroll
    for (int j = 0; j < 4; ++j) {
        const size_t gi = g4 + j * 64 + lane;
        const float4 a = a4[gi];
        const int4   m = m4[gi];
        const int4   t = t4[gi];
        uint32_t w = __builtin_amdgcn_cvt_pk_fp8_f32(a.x, a.y, 0u, false);
        w = __builtin_amdgcn_cvt_pk_fp8_f32(a.z, a.w, w, true);
        ws[j * 64 + lane]        = w;
        ws[MOFF + j * 64 + lane] = pack_lobytes(m);
        ws[TOFF + j * 64 + lane] = pack_lobytes(t);
        s_p += (a.x + a.y) + (a.z + a.w);
        q_p = fmaf(a.x, a.x, fmaf(a.y, a.y, fmaf(a.z, a.z, fmaf(a.w, a.w, q_p))));
    }

    // ---- consume: 16 steps of 64 elems (same-wave DS ordering, no barrier) ----
#pragma unroll 2
    for (int st = 0; st < 16; ++st) {
        const int off = st << 6;
        const uint4 v0 = *reinterpret_cast<const uint4*>(pv + off);
        const uint4 v1 = *reinterpret_cast<const uint4*>(pv + off + 16);
        const uint4 k0 = *reinterpret_cast<const uint4*>(pk + off);
        const uint4 k1 = *reinterpret_cast<const uint4*>(pk + off + 16);

        i32x8 fA1, fAa, fB1, fBa;
#define DOW(j, kw, vw) { \
        uint32_t mu, mt; \
        dow_masks<FAST>((kw) ^ patB, mu, mt); \
        fA1[j] = (int)(mt & 0x38383838u);  /* one-hot(t) * 1.0 (e4m3) */ \
        fAa[j] = (int)(mt & (vw)); \
        fB1[j] = (int)(mu & 0x38383838u); \
        fBa[j] = (int)(mu & (vw)); }
        DOW(0, k0.x, v0.x) DOW(1, k0.y, v0.y) DOW(2, k0.z, v0.z) DOW(3, k0.w, v0.w)
        DOW(4, k1.x, v1.x) DOW(5, k1.y, v1.y) DOW(6, k1.z, v1.z) DOW(7, k1.w, v1.w)
#undef DOW

        accC = __builtin_amdgcn_mfma_scale_f32_16x16x128_f8f6f4(
                   fA1, fB1, accC, 0, 0, 0, 0x7f7f7f7f, 0, 0x7f7f7f7f);
        accS = __builtin_amdgcn_mfma_scale_f32_16x16x128_f8f6f4(
                   fA1, fBa, accS, 0, 0, 0, 0x7f7f7f7f, 0, 0x7f7f7f7f);
        accQ = __builtin_amdgcn_mfma_scale_f32_16x16x128_f8f6f4(
                   fAa, fBa, accQ, 0, 0, 0, 0x7f7f7f7f, 0, 0x7f7f7f7f);
    }

    // ---- write this wave's stat table into its (now dead) stage slice ----
    // D layout: col = lane&15, row = grp*4 + reg (r8-proven)
    {
        float* tbl = (float*)ws;
#pragma unroll
        for (int r = 0; r < 4; ++r) {
            const int rr = grp * 4 + r;
            int addr = -1;
            if (rr <= 6)       addr = rr * 16 + n;             // mcc slot
            else if (rr <= 10) addr = 112 + (rr - 7) * 16 + n; // tr slot
            if (addr >= 0) {
                tbl[addr]       = accC[r];
                tbl[176 + addr] = accS[r];
                tbl[352 + addr] = accQ[r];
            }
        }
    }
#pragma unroll
    for (int off = 32; off; off >>= 1) {
        s_p += __shfl_xor(s_p, off, 64);
        q_p += __shfl_xor(q_p, off, 64);
    }
    if (lane == 0) { scal[wv][0] = s_p; scal[wv][1] = q_p; }
    __syncthreads();   // the ONLY barrier: merge point

    // ---- split epilogue: wave wv emits cols [wv*228, wv*228+228) ----
    const float* t0 = (const float*)smem;
    const float* t1 = (const float*)(smem + WSTR);
    auto TB = [&](int s, int c) -> float { return t0[s * 176 + c] + t1[s * 176 + c]; };

    int dm = 0, dt = 0;
    if (wv) {   // cols 454/455 live in wave 1's range
        for (int c0 = 0; c0 < 160; c0 += 64) {
            const int c = c0 + lane;
            bool pos = false;
            if (c >= 1 && c < 100)        pos = TB(0, c) > 0.f;
            else if (c >= 101 && c < 150) pos = TB(0, 112 + (c - 100)) > 0.f;
            dm += __popcll(__ballot(pos && c < 100));
            dt += __popcll(__ballot(pos && c >= 100));
        }
    }

    const float s_tot  = scal[0][0] + scal[1][0];
    const float ss_tot = scal[0][1] + scal[1][1];
    const float sl = (float)seq_lens[row];
    float* orow = out + (size_t)row * NCOL;

    for (int cc = lane; cc < 228; cc += 64) {
        const int col = wv * 228 + cc;
        float v;
        if (col == 0)      v = sl;
        else if (col == 1) v = s_tot;
        else if (col == 2) v = s_tot / (sl + EPS);
        else if (col == 3) {
            float a = fmaxf(ss_tot - s_tot * s_tot / (sl + EPS), 0.f);
            v = sqrtf(a / (fmaxf(sl - 1.f, 0.f) + EPS));
        }
        else if (col == 454) v = (float)dm;
        else if (col == 455) v = (float)dt;
        else {
            int base, C, toff;
            if (col < 304) { base = 4;   C = 100; toff = 0;   }
            else           { base = 304; C = 50;  toff = 112; }
            const int rel   = col - base;
            const int which = rel / C;
            const int c     = rel - which * C;
            const float cnt = (c > 0) ? TB(0, toff + c) : 0.f;  // e_cnt = cnt*mask
            const float sc  = TB(1, toff + c);
            const float ssc = TB(2, toff + c);
            if (which == 0)      v = cnt;
            else if (which == 1) v = sc / (cnt + EPS);
            else {
                float a = fmaxf(ssc - sc * sc / (cnt + EPS), 0.f);
                v = sqrtf(a / (fmaxf(cnt - 1.f, 0.f) + EPS));
            }
        }
        orow[col] = v;
    }
}

// ---------------- fused kernel (T == 2048): 2 waves per row ----------------
__global__ __launch_bounds__(128, 4) void agg_fused(
    const float4* __restrict__ a4,
    const int4* __restrict__ m4,
    const int4* __restrict__ t4,
    const int* __restrict__ seq_lens,
    const uint32_t* __restrict__ flag,
    float* __restrict__ out, int B)
{
    const int lane = threadIdx.x & 63;
    const int wv   = threadIdx.x >> 6;   // 0..1: half of the row
    const int row  = blockIdx.x;

    __shared__ uint32_t smem[2 * WSTR];  // 6.3 KB
    __shared__ float scal[2][2];

    if (*flag)
        agg_body<1>(a4, m4, t4, seq_lens, out, smem, scal, row, lane, wv);
    else
        agg_body<0>(a4, m4, t4, seq_lens, out, smem, scal, row, lane, wv);
}

// ---------------- fallback: proven r6 single-pass bf16 kernel ----------------
__global__ __launch_bounds__(512, 8) void agg2d_legacy(
    const float* __restrict__ amount,
    const int* __restrict__ mcc,
    const int* __restrict__ tr,
    const int* __restrict__ seq_lens,
    float* __restrict__ out, int T, int B)
{
    const int lane = threadIdx.x & 63;
    const int wv   = threadIdx.x >> 6;
    const int rl   = wv >> 1;
    const int half = wv & 1;
    const int row  = blockIdx.x * 4 + rl;
    const int n    = lane & 15;
    const int grp  = lane >> 4;
    const bool istr = (grp >= 2);
    const int ntc  = istr ? ((n - 7) & 15) : n;
    const uint32_t xorpat = (uint32_t)(((ntc << 4) | n) * 0x00010001u);
    const int roff = (grp & 1) * 8;

    __shared__ float part[4][2][3][176];
    __shared__ float scal[4][2][2];

    const int hb = half * (T >> 1);
    const float* pa = amount + (size_t)row * T + hb + roff;
    const int*   pk = (istr ? tr : mcc) + (size_t)row * T + hb + roff;

    f32x4 accC = {0.f,0.f,0.f,0.f};
    f32x4 accS = {0.f,0.f,0.f,0.f};
    f32x4 accQ = {0.f,0.f,0.f,0.f};

    const int nstep = T >> 5;
#pragma unroll 2
    for (int st = 0; st < nstep; ++st) {
        const int base = st << 4;
        const float4 a0 = *reinterpret_cast<const float4*>(pa + base);
        const float4 a1 = *reinterpret_cast<const float4*>(pa + base + 4);
        const int4   k0 = *reinterpret_cast<const int4*>(pk + base);
        const int4   k1 = *reinterpret_cast<const int4*>(pk + base + 4);

        const float av[8] = {a0.x,a0.y,a0.z,a0.w,a1.x,a1.y,a1.z,a1.w};
        const uint32_t kv[8] = {(uint32_t)k0.x,(uint32_t)k0.y,(uint32_t)k0.z,(uint32_t)k0.w,
                                (uint32_t)k1.x,(uint32_t)k1.y,(uint32_t)k1.z,(uint32_t)k1.w};

        u32x4 wA1, wAa, wB1, wBa;
#pragma unroll
        for (int i = 0; i < 4; ++i) {
            const uint32_t kpk = __builtin_amdgcn_perm(kv[2*i+1], kv[2*i], 0x05040100u);
            const uint32_t kx  = kpk ^ xorpat;
            const uint32_t mu  = hw_eqmask(kx & 0x000f000fu);
            const uint32_t mt  = hw_eqmask((kx >> 4) & 0x000f000fu);
            const uint32_t apk = __builtin_amdgcn_perm(
                __float_as_uint(av[2*i+1]), __float_as_uint(av[2*i]), 0x07060302u);
            wA1[i] = mt & 0x3f803f80u;
            wAa[i] = mt & apk;
            wB1[i] = mu & 0x3f803f80u;
            wBa[i] = mu & apk;
        }
        const bf16x8 fA1 = __builtin_bit_cast(bf16x8, wA1);
        const bf16x8 fAa = __builtin_bit_cast(bf16x8, wAa);
        const bf16x8 fB1 = __builtin_bit_cast(bf16x8, wB1);
        const bf16x8 fBa = __builtin_bit_cast(bf16x8, wBa);

        accC = __builtin_amdgcn_mfma_f32_16x16x32_bf16(fA1, fB1, accC, 0, 0, 0);
        accS = __builtin_amdgcn_mfma_f32_16x16x32_bf16(fA1, fBa, accS, 0, 0, 0);
        accQ = __builtin_amdgcn_mfma_f32_16x16x32_bf16(fAa, fBa, accQ, 0, 0, 0);
    }

    {
        float* my = &part[rl][half][0][0];
#pragma unroll
        for (int r = 0; r < 4; ++r) {
            const int rr = grp * 4 + r;
            int addr = -1;
            if (rr <= 6)       addr = rr * 16 + n;
            else if (rr <= 10) addr = 112 + (rr - 7) * 16 + n;
            if (addr >= 0) {
                my[addr]       = accC[r];
                my[176 + addr] = accS[r];
                my[352 + addr] = accQ[r];
            }
        }
    }
    float sS = 0.f, sQ = 0.f;
    if (grp == 0) {
        sS = accS[0] + accS[1] + accS[2] + accS[3];
        sQ = accQ[0] + accQ[1] + accQ[2] + accQ[3];
    } else if (grp == 1) {
        sS = accS[0] + accS[1] + accS[2];
        sQ = accQ[0] + accQ[1] + accQ[2];
    }
#pragma unroll
    for (int off = 32; off; off >>= 1) {
        sS += __shfl_xor(sS, off, 64);
        sQ += __shfl_xor(sQ, off, 64);
    }
    if (lane == 0) { scal[rl][half][0] = sS; scal[rl][half][1] = sQ; }
    __syncthreads();

    auto TB = [&](int s, int c) -> float {
        return part[rl][0][s][c] + part[rl][1][s][c];
    };

    int dm = 0, dt = 0;
    if (half) {
        for (int c0 = 0; c0 < 160; c0 += 64) {
            const int c = c0 + lane;
            bool pos = false;
            if (c >= 1 && c < 100)        pos = TB(0, c) > 0.f;
            else if (c >= 101 && c < 150) pos = TB(0, 112 + (c - 100)) > 0.f;
            dm += __popcll(__ballot(pos && c < 100));
            dt += __popcll(__ballot(pos && c >= 100));
        }
    }

    const float sl     = (float)seq_lens[row];
    const float s_tot  = scal[rl][0][0] + scal[rl][1][0];
    const float ss_tot = scal[rl][0][1] + scal[rl][1][1];
    float* orow = out + (size_t)row * NCOL;

    for (int cc = lane; cc < 228; cc += 64) {
        const int col = half * 228 + cc;
        float v;
        if (col == 0)      v = sl;
        else if (col == 1) v = s_tot;
        else if (col == 2) v = s_tot / (sl + EPS);
        else if (col == 3) {
            float a = fmaxf(ss_tot - s_tot * s_tot / (sl + EPS), 0.f);
            v = sqrtf(a / (fmaxf(sl - 1.f, 0.f) + EPS));
        }
        else if (col == 454) v = (float)dm;
        else if (col == 455) v = (float)dt;
        else {
            int base, C, toff;
            if (col < 304) { base = 4;   C = 100; toff = 0;   }
            else           { base = 304; C = 50;  toff = 112; }
            const int rel   = col - base;
            const int which = rel / C;
            const int c     = rel - which * C;
            const float cnt = (c > 0) ? TB(0, toff + c) : 0.f;
            const float sc  = TB(1, toff + c);
            const float ssc = TB(2, toff + c);
            if (which == 0)      v = cnt;
            else if (which == 1) v = sc / (cnt + EPS);
            else {
                float a = fmaxf(ssc - sc * sc / (cnt + EPS), 0.f);
                v = sqrtf(a / (fmaxf(cnt - 1.f, 0.f) + EPS));
            }
        }
        orow[col] = v;
    }
}

extern "C" void kernel_launch(void* const* d_in, const int* in_sizes, int n_in,
                              void* d_out, int out_size, void* d_ws, size_t ws_size,
                              hipStream_t stream) {
    const float* amount   = (const float*)d_in[0];
    const int*   mcc      = (const int*)d_in[1];
    const int*   tr_type  = (const int*)d_in[2];
    const int*   seq_lens = (const int*)d_in[3];
    float*       out      = (float*)d_out;

    const int B = in_sizes[3];            // 4096
    const int T = in_sizes[0] / B;        // 2048

    if (T == 2048 && ws_size >= 4) {
        uint32_t* flag = (uint32_t*)d_ws;
        perm_probe<<<1, 64, 0, stream>>>(flag);
        agg_fused<<<B, 128, 0, stream>>>(
            (const float4*)amount, (const int4*)mcc, (const int4*)tr_type,
            seq_lens, flag, out, B);
    } else {
        agg2d_legacy<<<(B + 3) / 4, 512, 0, stream>>>(amount, mcc, tr_type, seq_lens, out, T, B);
    }
}

// Round 16
// 45.738 us; speedup vs baseline: 1.0732x; 1.0732x over previous
//
#include <hip/hip_runtime.h>
#include <stdint.h>

// AggFeatureModel, FUSED, 2-waves-per-row (T==2048 path), r16:
//  r14 structure; consume loop restructured against mask REMATERIALIZATION
//  (r15 diagnosis: VALUBusy-derived inst count ~2x static count at VGPR=52
//  -> allocator recomputes remat-eligible mask chains instead of holding):
//   - masks computed ONCE per step into mu[8]/mt[8], pinned via asm "+v"
//   - MFMA order C:(A1,B1) -> S:(Aa,B1) -> Q:(Aa,Ba) so fragments die early
//     (S uses the symmetry sum a*[t]*[u]: value can ride on A instead of B)
//   - mask expansion (m<<8)-m == m*255 exactly (full-rate, no v_mul risk)
//   - no probe dispatch (r15's perm gamble abandoned: zero evidence gained)
// Fallback: proven r6 bf16 single-pass kernel for T != 2048.

#define NCOL 456
static constexpr float EPS = 1e-9f;

typedef __bf16 bf16x8 __attribute__((ext_vector_type(8)));
typedef float  f32x4  __attribute__((ext_vector_type(4)));
typedef int    i32x8  __attribute__((ext_vector_type(8)));
typedef unsigned int u32x4 __attribute__((ext_vector_type(4)));
typedef short  s16x2  __attribute__((ext_vector_type(2)));

__device__ __forceinline__ uint32_t hw_eqmask(uint32_t h) {
    // halfword SWAR eq-zero (legacy kernel)
    const uint32_t s = 0x80008000u - h;
    const s16x2 m = __builtin_bit_cast(s16x2, s) >> 15;
    return __builtin_bit_cast(uint32_t, m);
}

__device__ __forceinline__ uint32_t pack_lobytes(int4 m) {
    // [w0,z0,y0,x0] from the low bytes of 4 ints: 3 v_perm (r10-proven)
    const uint32_t p01 = __builtin_amdgcn_perm((uint32_t)m.y, (uint32_t)m.x, 0x00000400u);
    const uint32_t p23 = __builtin_amdgcn_perm((uint32_t)m.w, (uint32_t)m.z, 0x00000400u);
    return __builtin_amdgcn_perm(p23, p01, 0x05040100u);
}

// byte-bits (0/1 per byte) -> 0xFF/0x00 bytes: (m<<8)-m == m*255 exactly.
__device__ __forceinline__ uint32_t bytemask_expand(uint32_t m) {
    return (m << 8) - m;
}

// wave LDS slice (uint32 words): [0,256) fp8 val, [256,512) mcc keys,
// [528,784) tr keys (+16-word pad separates broadcast-group banks).
// After consume, slice is reused as the wave's 528-float stat table.
#define WSTR 784
#define MOFF 256
#define TOFF 528

// ---------------- fused kernel (T == 2048): 2 waves per row ----------------
__global__ __launch_bounds__(128, 4) void agg_fused(
    const float4* __restrict__ a4,
    const int4* __restrict__ m4,
    const int4* __restrict__ t4,
    const int* __restrict__ seq_lens,
    float* __restrict__ out, int B)
{
    const int lane = threadIdx.x & 63;
    const int wv   = threadIdx.x >> 6;   // 0..1: half of the row
    const int row  = blockIdx.x;
    const int n    = lane & 15;
    const int grp  = lane >> 4;
    const bool istr = (grp >= 2);
    const int ntc  = istr ? ((n - 7) & 15) : n;
    const uint32_t patB = (uint32_t)(((ntc << 4) | n) * 0x01010101u);

    __shared__ uint32_t smem[2 * WSTR];  // 6.3 KB
    __shared__ float scal[2][2];
    uint32_t* ws = smem + wv * WSTR;

    f32x4 accC = {0.f,0.f,0.f,0.f};
    f32x4 accS = {0.f,0.f,0.f,0.f};
    f32x4 accQ = {0.f,0.f,0.f,0.f};
    float s_p = 0.f, q_p = 0.f;

    const uint8_t* pv = (const uint8_t*)ws + ((grp & 1) << 5);
    const uint8_t* pk = (const uint8_t*)(ws + (istr ? TOFF : MOFF)) + ((grp & 1) << 5);

    // ---- stage this wave's half-row: 4 x {float4,int4,int4}, coalesced ----
    const size_t g4 = (size_t)row * 512 + wv * 256;   // float4 units
#pragma unroll
    for (int j = 0; j < 4; ++j) {
        const size_t gi = g4 + j * 64 + lane;
        const float4 a = a4[gi];
        const int4   m = m4[gi];
        const int4   t = t4[gi];
        uint32_t w = __builtin_amdgcn_cvt_pk_fp8_f32(a.x, a.y, 0u, false);
        w = __builtin_amdgcn_cvt_pk_fp8_f32(a.z, a.w, w, true);
        ws[j * 64 + lane]        = w;
        ws[MOFF + j * 64 + lane] = pack_lobytes(m);
        ws[TOFF + j * 64 + lane] = pack_lobytes(t);
        s_p += (a.x + a.y) + (a.z + a.w);
        q_p = fmaf(a.x, a.x, fmaf(a.y, a.y, fmaf(a.z, a.z, fmaf(a.w, a.w, q_p))));
    }

    // ---- consume: 16 steps of 64 elems (same-wave DS ordering, no barrier) ----
#pragma unroll 2
    for (int st = 0; st < 16; ++st) {
        const int off = st << 6;
        const uint4 v0 = *reinterpret_cast<const uint4*>(pv + off);
        const uint4 v1 = *reinterpret_cast<const uint4*>(pv + off + 16);
        const uint4 k0 = *reinterpret_cast<const uint4*>(pk + off);
        const uint4 k1 = *reinterpret_cast<const uint4*>(pk + off + 16);

        const uint32_t kw[8] = {k0.x,k0.y,k0.z,k0.w,k1.x,k1.y,k1.z,k1.w};
        const uint32_t vw[8] = {v0.x,v0.y,v0.z,v0.w,v1.x,v1.y,v1.z,v1.w};

        // masks once per step, pinned against rematerialization
        uint32_t mu[8], mt[8];
#pragma unroll
        for (int j = 0; j < 8; ++j) {
            const uint32_t kx = kw[j] ^ patB;
            const uint32_t hu = kx & 0x0f0f0f0fu;
            mu[j] = bytemask_expand(((0x80808080u - hu) & 0x80808080u) >> 7);
            const uint32_t ht = (kx >> 4) & 0x0f0f0f0fu;
            mt[j] = bytemask_expand(((0x80808080u - ht) & 0x80808080u) >> 7);
            asm volatile("" : "+v"(mu[j]), "+v"(mt[j]));
        }

        // C: one-hot(t) x one-hot(u)
        i32x8 fA1, fB1;
#pragma unroll
        for (int j = 0; j < 8; ++j) {
            fA1[j] = (int)(mt[j] & 0x38383838u);   // 1.0 in e4m3
            fB1[j] = (int)(mu[j] & 0x38383838u);
        }
        accC = __builtin_amdgcn_mfma_scale_f32_16x16x128_f8f6f4(
                   fA1, fB1, accC, 0, 0, 0, 0x7f7f7f7f, 0, 0x7f7f7f7f);

        // S: (a*one-hot(t)) x one-hot(u)  [same bilinear form as (A1,Ba)]
        i32x8 fAa;
#pragma unroll
        for (int j = 0; j < 8; ++j) fAa[j] = (int)(mt[j] & vw[j]);
        accS = __builtin_amdgcn_mfma_scale_f32_16x16x128_f8f6f4(
                   fAa, fB1, accS, 0, 0, 0, 0x7f7f7f7f, 0, 0x7f7f7f7f);

        // Q: (a*one-hot(t)) x (a*one-hot(u))
        i32x8 fBa;
#pragma unroll
        for (int j = 0; j < 8; ++j) fBa[j] = (int)(mu[j] & vw[j]);
        accQ = __builtin_amdgcn_mfma_scale_f32_16x16x128_f8f6f4(
                   fAa, fBa, accQ, 0, 0, 0, 0x7f7f7f7f, 0, 0x7f7f7f7f);
    }

    // ---- write this wave's stat table into its (now dead) stage slice ----
    // D layout: col = lane&15, row = grp*4 + reg (r8-proven)
    {
        float* tbl = (float*)ws;
#pragma unroll
        for (int r = 0; r < 4; ++r) {
            const int rr = grp * 4 + r;
            int addr = -1;
            if (rr <= 6)       addr = rr * 16 + n;             // mcc slot
            else if (rr <= 10) addr = 112 + (rr - 7) * 16 + n; // tr slot
            if (addr >= 0) {
                tbl[addr]       = accC[r];
                tbl[176 + addr] = accS[r];
                tbl[352 + addr] = accQ[r];
            }
        }
    }
#pragma unroll
    for (int off = 32; off; off >>= 1) {
        s_p += __shfl_xor(s_p, off, 64);
        q_p += __shfl_xor(q_p, off, 64);
    }
    if (lane == 0) { scal[wv][0] = s_p; scal[wv][1] = q_p; }
    __syncthreads();   // the ONLY barrier: merge point

    // ---- split epilogue: wave wv emits cols [wv*228, wv*228+228) ----
    const float* t0 = (const float*)smem;
    const float* t1 = (const float*)(smem + WSTR);
    auto TB = [&](int s, int c) -> float { return t0[s * 176 + c] + t1[s * 176 + c]; };

    int dm = 0, dt = 0;
    if (wv) {   // cols 454/455 live in wave 1's range
        for (int c0 = 0; c0 < 160; c0 += 64) {
            const int c = c0 + lane;
            bool pos = false;
            if (c >= 1 && c < 100)        pos = TB(0, c) > 0.f;
            else if (c >= 101 && c < 150) pos = TB(0, 112 + (c - 100)) > 0.f;
            dm += __popcll(__ballot(pos && c < 100));
            dt += __popcll(__ballot(pos && c >= 100));
        }
    }

    const float s_tot  = scal[0][0] + scal[1][0];
    const float ss_tot = scal[0][1] + scal[1][1];
    const float sl = (float)seq_lens[row];
    float* orow = out + (size_t)row * NCOL;

    for (int cc = lane; cc < 228; cc += 64) {
        const int col = wv * 228 + cc;
        float v;
        if (col == 0)      v = sl;
        else if (col == 1) v = s_tot;
        else if (col == 2) v = s_tot / (sl + EPS);
        else if (col == 3) {
            float a = fmaxf(ss_tot - s_tot * s_tot / (sl + EPS), 0.f);
            v = sqrtf(a / (fmaxf(sl - 1.f, 0.f) + EPS));
        }
        else if (col == 454) v = (float)dm;
        else if (col == 455) v = (float)dt;
        else {
            int base, C, toff;
            if (col < 304) { base = 4;   C = 100; toff = 0;   }
            else           { base = 304; C = 50;  toff = 112; }
            const int rel   = col - base;
            const int which = rel / C;
            const int c     = rel - which * C;
            const float cnt = (c > 0) ? TB(0, toff + c) : 0.f;  // e_cnt = cnt*mask
            const float sc  = TB(1, toff + c);
            const float ssc = TB(2, toff + c);
            if (which == 0)      v = cnt;
            else if (which == 1) v = sc / (cnt + EPS);
            else {
                float a = fmaxf(ssc - sc * sc / (cnt + EPS), 0.f);
                v = sqrtf(a / (fmaxf(cnt - 1.f, 0.f) + EPS));
            }
        }
        orow[col] = v;
    }
}

// ---------------- fallback: proven r6 single-pass bf16 kernel ----------------
__global__ __launch_bounds__(512, 8) void agg2d_legacy(
    const float* __restrict__ amount,
    const int* __restrict__ mcc,
    const int* __restrict__ tr,
    const int* __restrict__ seq_lens,
    float* __restrict__ out, int T, int B)
{
    const int lane = threadIdx.x & 63;
    const int wv   = threadIdx.x >> 6;
    const int rl   = wv >> 1;
    const int half = wv & 1;
    const int row  = blockIdx.x * 4 + rl;
    const int n    = lane & 15;
    const int grp  = lane >> 4;
    const bool istr = (grp >= 2);
    const int ntc  = istr ? ((n - 7) & 15) : n;
    const uint32_t xorpat = (uint32_t)(((ntc << 4) | n) * 0x00010001u);
    const int roff = (grp & 1) * 8;

    __shared__ float part[4][2][3][176];
    __shared__ float scal[4][2][2];

    const int hb = half * (T >> 1);
    const float* pa = amount + (size_t)row * T + hb + roff;
    const int*   pk = (istr ? tr : mcc) + (size_t)row * T + hb + roff;

    f32x4 accC = {0.f,0.f,0.f,0.f};
    f32x4 accS = {0.f,0.f,0.f,0.f};
    f32x4 accQ = {0.f,0.f,0.f,0.f};

    const int nstep = T >> 5;
#pragma unroll 2
    for (int st = 0; st < nstep; ++st) {
        const int base = st << 4;
        const float4 a0 = *reinterpret_cast<const float4*>(pa + base);
        const float4 a1 = *reinterpret_cast<const float4*>(pa + base + 4);
        const int4   k0 = *reinterpret_cast<const int4*>(pk + base);
        const int4   k1 = *reinterpret_cast<const int4*>(pk + base + 4);

        const float av[8] = {a0.x,a0.y,a0.z,a0.w,a1.x,a1.y,a1.z,a1.w};
        const uint32_t kv[8] = {(uint32_t)k0.x,(uint32_t)k0.y,(uint32_t)k0.z,(uint32_t)k0.w,
                                (uint32_t)k1.x,(uint32_t)k1.y,(uint32_t)k1.z,(uint32_t)k1.w};

        u32x4 wA1, wAa, wB1, wBa;
#pragma unroll
        for (int i = 0; i < 4; ++i) {
            const uint32_t kpk = __builtin_amdgcn_perm(kv[2*i+1], kv[2*i], 0x05040100u);
            const uint32_t kx  = kpk ^ xorpat;
            const uint32_t mu  = hw_eqmask(kx & 0x000f000fu);
            const uint32_t mt  = hw_eqmask((kx >> 4) & 0x000f000fu);
            const uint32_t apk = __builtin_amdgcn_perm(
                __float_as_uint(av[2*i+1]), __float_as_uint(av[2*i]), 0x07060302u);
            wA1[i] = mt & 0x3f803f80u;
            wAa[i] = mt & apk;
            wB1[i] = mu & 0x3f803f80u;
            wBa[i] = mu & apk;
        }
        const bf16x8 fA1 = __builtin_bit_cast(bf16x8, wA1);
        const bf16x8 fAa = __builtin_bit_cast(bf16x8, wAa);
        const bf16x8 fB1 = __builtin_bit_cast(bf16x8, wB1);
        const bf16x8 fBa = __builtin_bit_cast(bf16x8, wBa);

        accC = __builtin_amdgcn_mfma_f32_16x16x32_bf16(fA1, fB1, accC, 0, 0, 0);
        accS = __builtin_amdgcn_mfma_f32_16x16x32_bf16(fA1, fBa, accS, 0, 0, 0);
        accQ = __builtin_amdgcn_mfma_f32_16x16x32_bf16(fAa, fBa, accQ, 0, 0, 0);
    }

    {
        float* my = &part[rl][half][0][0];
#pragma unroll
        for (int r = 0; r < 4; ++r) {
            const int rr = grp * 4 + r;
            int addr = -1;
            if (rr <= 6)       addr = rr * 16 + n;
            else if (rr <= 10) addr = 112 + (rr - 7) * 16 + n;
            if (addr >= 0) {
                my[addr]       = accC[r];
                my[176 + addr] = accS[r];
                my[352 + addr] = accQ[r];
            }
        }
    }
    float sS = 0.f, sQ = 0.f;
    if (grp == 0) {
        sS = accS[0] + accS[1] + accS[2] + accS[3];
        sQ = accQ[0] + accQ[1] + accQ[2] + accQ[3];
    } else if (grp == 1) {
        sS = accS[0] + accS[1] + accS[2];
        sQ = accQ[0] + accQ[1] + accQ[2];
    }
#pragma unroll
    for (int off = 32; off; off >>= 1) {
        sS += __shfl_xor(sS, off, 64);
        sQ += __shfl_xor(sQ, off, 64);
    }
    if (lane == 0) { scal[rl][half][0] = sS; scal[rl][half][1] = sQ; }
    __syncthreads();

    auto TB = [&](int s, int c) -> float {
        return part[rl][0][s][c] + part[rl][1][s][c];
    };

    int dm = 0, dt = 0;
    if (half) {
        for (int c0 = 0; c0 < 160; c0 += 64) {
            const int c = c0 + lane;
            bool pos = false;
            if (c >= 1 && c < 100)        pos = TB(0, c) > 0.f;
            else if (c >= 101 && c < 150) pos = TB(0, 112 + (c - 100)) > 0.f;
            dm += __popcll(__ballot(pos && c < 100));
            dt += __popcll(__ballot(pos && c >= 100));
        }
    }

    const float sl     = (float)seq_lens[row];
    const float s_tot  = scal[rl][0][0] + scal[rl][1][0];
    const float ss_tot = scal[rl][0][1] + scal[rl][1][1];
    float* orow = out + (size_t)row * NCOL;

    for (int cc = lane; cc < 228; cc += 64) {
        const int col = half * 228 + cc;
        float v;
        if (col == 0)      v = sl;
        else if (col == 1) v = s_tot;
        else if (col == 2) v = s_tot / (sl + EPS);
        else if (col == 3) {
            float a = fmaxf(ss_tot - s_tot * s_tot / (sl + EPS), 0.f);
            v = sqrtf(a / (fmaxf(sl - 1.f, 0.f) + EPS));
        }
        else if (col == 454) v = (float)dm;
        else if (col == 455) v = (float)dt;
        else {
            int base, C, toff;
            if (col < 304) { base = 4;   C = 100; toff = 0;   }
            else           { base = 304; C = 50;  toff = 112; }
            const int rel   = col - base;
            const int which = rel / C;
            const int c     = rel - which * C;
            const float cnt = (c > 0) ? TB(0, toff + c) : 0.f;
            const float sc  = TB(1, toff + c);
            const float ssc = TB(2, toff + c);
            if (which == 0)      v = cnt;
            else if (which == 1) v = sc / (cnt + EPS);
            else {
                float a = fmaxf(ssc - sc * sc / (cnt + EPS), 0.f);
                v = sqrtf(a / (fmaxf(cnt - 1.f, 0.f) + EPS));
            }
        }
        orow[col] = v;
    }
}

extern "C" void kernel_launch(void* const* d_in, const int* in_sizes, int n_in,
                              void* d_out, int out_size, void* d_ws, size_t ws_size,
                              hipStream_t stream) {
    const float* amount   = (const float*)d_in[0];
    const int*   mcc      = (const int*)d_in[1];
    const int*   tr_type  = (const int*)d_in[2];
    const int*   seq_lens = (const int*)d_in[3];
    float*       out      = (float*)d_out;

    const int B = in_sizes[3];            // 4096
    const int T = in_sizes[0] / B;        // 2048

    if (T == 2048) {
        agg_fused<<<B, 128, 0, stream>>>(
            (const float4*)amount, (const int4*)mcc, (const int4*)tr_type,
            seq_lens, out, B);
    } else {
        agg2d_legacy<<<(B + 3) / 4, 512, 0, stream>>>(amount, mcc, tr_type, seq_lens, out, T, B);
    }
}